// Round 1
// baseline (37272.412 us; speedup 1.0000x reference)
//
#include <hip/hip_runtime.h>
#include <math.h>
#include <stdint.h>

// ---------------------------------------------------------------------------
// RelationModule on MI355X.
// Layouts (all activations in [n=(b,t)][d] "tbd" order so K is contiguous):
//   h    fp32 [Nn][2048]   : bdt tensor, element (b,d,t) at (b*16+t)*2048+d
//   u2   fp16 [Nn][4096]   : [uh | ul] hi/lo split of u*2^-k (per-iter scale)
//   TPG  fp32 [3072][Nn]   : theta-hat rows 0..1023, phi-hat 1024.., g-hat 2048..
//   ctx  fp16 [Nn][2048]   : [ch | cl] hi/lo split of context*2^(-k-2)
// Weights (fp16, *2^12): A1w [3072][6144] = [Wh|Wh|Wl] per row; Wc6 [2048][3072].
// Precision: 3-term hi/lo fp16 GEMMs (err ~ fp32 accum noise) because the
// softmax is an exact argmax from iter>=3 and any bf16-level score error flips
// selections vs the np reference (catastrophic at 2% absmax threshold).
// ---------------------------------------------------------------------------

typedef float  floatx4 __attribute__((ext_vector_type(4)));
typedef float  floatx2 __attribute__((ext_vector_type(2)));
typedef _Float16 half8 __attribute__((ext_vector_type(8)));
typedef short  short8 __attribute__((ext_vector_type(8)));
typedef unsigned short ushort2v __attribute__((ext_vector_type(2)));
typedef unsigned short ushort4v __attribute__((ext_vector_type(4)));

#define BIGK (1 << 28)

__device__ __forceinline__ unsigned short h_bits(_Float16 h) {
  return __builtin_bit_cast(unsigned short, h);
}

__device__ __forceinline__ void gld_lds16(const unsigned short* g, unsigned short* l) {
  __builtin_amdgcn_global_load_lds(
      (const __attribute__((address_space(1))) unsigned int*)g,
      (__attribute__((address_space(3))) unsigned int*)l, 16, 0, 0);
}

// ---------------------------------------------------------------------------
// Generic f16 GEMM, C[m][n] = sum_k A[m][k]*B[n][k]  (both operands k-contig).
// 128x128 tile, BK=64, 4 waves each 64x64 (4x4 MFMA 16x16x32 f16).
// kfA/kfB: k-fold points for the hi/lo 3-term trick (BIGK = disabled).
// EPI 0: plain fp32 store to out0 (ld ldo). (+ optional blockIdx.z K-split)
// EPI 2: residual-block epilogue: out0 = h (ld ldo=2048), out1 = u2 (ld 2*ldo).
// ---------------------------------------------------------------------------
template <int EPI>
__global__ __launch_bounds__(256, 2)
void gemm_f16(const unsigned short* __restrict__ A, int lda, int kfA,
              const unsigned short* __restrict__ B, int ldb, int kfB,
              int K, float* __restrict__ out0, unsigned short* __restrict__ out1,
              int ldo, const float* __restrict__ tbl,
              float cmult, float uscale, int writeU, long zAB, long zO) {
  __shared__ unsigned short As[128 * 64];
  __shared__ unsigned short Bs[128 * 64];
  if (zAB) { A += (long)blockIdx.z * zAB; B += (long)blockIdx.z * zAB; }
  if (zO) { out0 += (long)blockIdx.z * zO; }
  const int tid = threadIdx.x;
  const int w = tid >> 6, l = tid & 63;
  const int quad = l >> 4, lr = l & 15;
  const int m0 = blockIdx.x * 128, n0 = blockIdx.y * 128;
  const int wm = (w & 1) * 64, wn = (w >> 1) * 64;

  floatx4 acc[4][4];
#pragma unroll
  for (int a = 0; a < 4; a++)
#pragma unroll
    for (int b = 0; b < 4; b++)
#pragma unroll
      for (int q = 0; q < 4; q++) acc[a][b][q] = 0.f;

  for (int k0 = 0; k0 < K; k0 += 64) {
    int ka = (k0 >= kfA) ? k0 - kfA : k0;
    int kb = (k0 >= kfB) ? k0 - kfB : k0;
    __syncthreads();
#pragma unroll
    for (int i = 0; i < 4; i++) {
      int c = i * 256 + tid;
      int m = c >> 3, kc = (c & 7) * 8;
      gld_lds16(A + (size_t)(m0 + m) * lda + ka + kc, As + c * 8);
      gld_lds16(B + (size_t)(n0 + m) * ldb + kb + kc, Bs + c * 8);
    }
    __syncthreads();
#pragma unroll
    for (int kk = 0; kk < 64; kk += 32) {
      short8 af[4], bf[4];
#pragma unroll
      for (int mi = 0; mi < 4; mi++)
        af[mi] = *(const short8*)(As + (wm + mi * 16 + lr) * 64 + kk + quad * 8);
#pragma unroll
      for (int ni = 0; ni < 4; ni++)
        bf[ni] = *(const short8*)(Bs + (wn + ni * 16 + lr) * 64 + kk + quad * 8);
#pragma unroll
      for (int mi = 0; mi < 4; mi++)
#pragma unroll
        for (int ni = 0; ni < 4; ni++)
          acc[mi][ni] = __builtin_amdgcn_mfma_f32_16x16x32_f16(
              __builtin_bit_cast(half8, af[mi]),
              __builtin_bit_cast(half8, bf[ni]), acc[mi][ni], 0, 0, 0);
    }
  }

  if (EPI == 0) {
#pragma unroll
    for (int mi = 0; mi < 4; mi++)
#pragma unroll
      for (int i2 = 0; i2 < 4; i2++) {
        int row = m0 + wm + mi * 16 + quad * 4 + i2;
#pragma unroll
        for (int ni = 0; ni < 4; ni++) {
          int col = n0 + wn + ni * 16 + lr;
          out0[(size_t)row * ldo + col] = acc[mi][ni][i2];
        }
      }
  } else {
    // EPI 2: rows = n (b,t), cols = d.  Replicate np's elementwise op order.
    float invv[4], bb[4];
#pragma unroll
    for (int ni = 0; ni < 4; ni++) {
      int d = n0 + wn + ni * 16 + lr;
      invv[ni] = tbl[d];
      bb[ni] = tbl[2048 + d];
    }
#pragma unroll
    for (int mi = 0; mi < 4; mi++)
#pragma unroll
      for (int i2 = 0; i2 < 4; i2++) {
        size_t row = (size_t)(m0 + wm + mi * 16 + quad * 4 + i2);
#pragma unroll
        for (int ni = 0; ni < 4; ni++) {
          int d = n0 + wn + ni * 16 + lr;
          size_t off = row * (size_t)ldo + d;
          float hold = out0[off];
          float ctxv = acc[mi][ni][i2] * cmult;  // true-scale W@context
          float u = __fadd_rn(__fmul_rn(hold, invv[ni]), bb[ni]);   // bn(h)
          float cb = __fadd_rn(__fmul_rn(ctxv, invv[ni]), bb[ni]);  // bn(ctx)
          float o1 = __fadd_rn(cb, u);
          float h2 = __fadd_rn(__fmul_rn(o1, invv[ni]), bb[ni]);    // bn(o1)
          float hn = __fadd_rn(h2, hold);                           // + residual
          out0[off] = hn;
          float un = __fadd_rn(__fmul_rn(hn, invv[ni]), bb[ni]);    // next u
          acc[mi][ni][i2] = un * uscale;
        }
      }
    if (writeU) {
      // LDS-stage u-hi then u-lo for coalesced 16B fp16 stores.
      unsigned short* st = (w < 2) ? (As + w * 4096) : (Bs + (w - 2) * 4096);
      __syncthreads();
#pragma unroll
      for (int mi = 0; mi < 4; mi++)
#pragma unroll
        for (int i2 = 0; i2 < 4; i2++) {
          int rr = mi * 16 + quad * 4 + i2;
#pragma unroll
          for (int ni = 0; ni < 4; ni++)
            st[rr * 64 + ni * 16 + lr] = h_bits((_Float16)acc[mi][ni][i2]);
        }
      __syncthreads();
#pragma unroll
      for (int j = 0; j < 8; j++) {
        int chk = j * 64 + l, rr = chk >> 3, c8 = (chk & 7) * 8;
        short8 v = *(const short8*)(st + rr * 64 + c8);
        *(short8*)(out1 + (size_t)(m0 + wm + rr) * (2 * ldo) + n0 + wn + c8) = v;
      }
      __syncthreads();
#pragma unroll
      for (int mi = 0; mi < 4; mi++)
#pragma unroll
        for (int i2 = 0; i2 < 4; i2++) {
          int rr = mi * 16 + quad * 4 + i2;
#pragma unroll
          for (int ni = 0; ni < 4; ni++) {
            float u = acc[mi][ni][i2];
            _Float16 hh = (_Float16)u;
            st[rr * 64 + ni * 16 + lr] = h_bits((_Float16)(u - (float)hh));
          }
        }
      __syncthreads();
#pragma unroll
      for (int j = 0; j < 8; j++) {
        int chk = j * 64 + l, rr = chk >> 3, c8 = (chk & 7) * 8;
        short8 v = *(const short8*)(st + rr * 64 + c8);
        *(short8*)(out1 + (size_t)(m0 + wm + rr) * (2 * ldo) + ldo + n0 + wn + c8) = v;
      }
    }
  }
}

// ---------------------------------------------------------------------------
// Attention per b: scores (fp64 acc) -> softmax -> context, hi/lo fp16 out.
// ---------------------------------------------------------------------------
__global__ __launch_bounds__(256)
void attn_kernel(const float* __restrict__ TPG, unsigned short* __restrict__ ctx,
                 int Nn, float smult, float gmult, float scmult) {
  __shared__ float sTh[128 * 16];
  __shared__ float sPh[128 * 16];
  __shared__ float sGc[128 * 17];
  __shared__ float sS[256];
  __shared__ float sA[256];
  const int b = blockIdx.x, tid = threadIdx.x;
  const int t = tid >> 4, s = tid & 15;
  double acc = 0.0;
  for (int cc = 0; cc < 8; cc++) {
#pragma unroll
    for (int i = 0; i < 2; i++) {
      int fi = i * 256 + tid, r = fi >> 2, c = (fi & 3) * 4;
      *(floatx4*)&sTh[r * 16 + c] =
          *(const floatx4*)&TPG[(size_t)(cc * 128 + r) * Nn + b * 16 + c];
      *(floatx4*)&sPh[r * 16 + c] =
          *(const floatx4*)&TPG[(size_t)(1024 + cc * 128 + r) * Nn + b * 16 + c];
    }
    __syncthreads();
    for (int o = 0; o < 128; o++)
      acc += (double)sTh[o * 16 + t] * (double)sPh[o * 16 + s];
    __syncthreads();
  }
  float sv = (float)(acc * (double)smult);
  sS[tid] = sv;
  __syncthreads();
  float mx = sS[t * 16];
#pragma unroll
  for (int j = 1; j < 16; j++) mx = fmaxf(mx, sS[t * 16 + j]);
  float e = expf(sv - mx);
  sA[tid] = e;
  __syncthreads();
  float sum = 0.f;
#pragma unroll
  for (int j = 0; j < 16; j++) sum += sA[t * 16 + j];
  float alpha = e / sum;
  __syncthreads();
  sA[tid] = alpha;
  __syncthreads();
  const int t2 = tid >> 7, ol = tid & 127;
  for (int cc = 0; cc < 8; cc++) {
#pragma unroll
    for (int i = 0; i < 2; i++) {
      int fi = i * 256 + tid, r = fi >> 2, c = (fi & 3) * 4;
      floatx4 g = *(const floatx4*)&TPG[(size_t)(2048 + cc * 128 + r) * Nn + b * 16 + c];
      sGc[r * 17 + c + 0] = g[0] * gmult;
      sGc[r * 17 + c + 1] = g[1] * gmult;
      sGc[r * 17 + c + 2] = g[2] * gmult;
      sGc[r * 17 + c + 3] = g[3] * gmult;
    }
    __syncthreads();
#pragma unroll
    for (int tt = 0; tt < 8; tt++) {
      int tc = t2 + tt * 2;
      float cv = 0.f;
#pragma unroll
      for (int s2 = 0; s2 < 16; s2++) cv += sA[tc * 16 + s2] * sGc[ol * 17 + s2];
      float cs = cv * scmult;
      _Float16 chh = (_Float16)cs;
      _Float16 cll = (_Float16)(cs - (float)chh);
      size_t base = ((size_t)b * 16 + tc) * 2048 + cc * 128 + ol;
      ctx[base] = h_bits(chh);
      ctx[base + 1024] = h_bits(cll);
    }
    __syncthreads();
  }
}

// ---------------------------------------------------------------------------
// Elementwise / transpose / prep kernels
// ---------------------------------------------------------------------------
__global__ __launch_bounds__(256)
void e0_kernel(const float* __restrict__ x, float* __restrict__ h,
               unsigned short* __restrict__ u2, const float* __restrict__ tbl,
               int b0, float uscale) {
  __shared__ float sx[16 * 129];
  const int bl = blockIdx.x, d0 = blockIdx.y * 128, tid = threadIdx.x;
  const float* xb = x + (size_t)(b0 + bl) * 32768;
#pragma unroll
  for (int i = 0; i < 2; i++) {
    int fi = i * 256 + tid, r = fi >> 2, c = (fi & 3) * 4;
    floatx4 v = *(const floatx4*)&xb[(d0 + r) * 16 + c];
    sx[(c + 0) * 129 + r] = v[0];
    sx[(c + 1) * 129 + r] = v[1];
    sx[(c + 2) * 129 + r] = v[2];
    sx[(c + 3) * 129 + r] = v[3];
  }
  __syncthreads();
  const int t4 = tid >> 6, dl = (tid & 63) * 2;
#pragma unroll
  for (int i = 0; i < 4; i++) {
    int t = t4 * 4 + i;
    int d = d0 + dl;
    float x0 = sx[t * 129 + dl], x1 = sx[t * 129 + dl + 1];
    size_t n = (size_t)bl * 16 + t;
    floatx2 hv; hv[0] = x0; hv[1] = x1;
    *(floatx2*)&h[n * 2048 + d] = hv;
    float i0 = tbl[d], i1 = tbl[d + 1], q0 = tbl[2048 + d], q1 = tbl[2048 + d + 1];
    float u0 = __fadd_rn(__fmul_rn(x0, i0), q0) * uscale;
    float u1 = __fadd_rn(__fmul_rn(x1, i1), q1) * uscale;
    _Float16 a0 = (_Float16)u0, a1 = (_Float16)u1;
    ushort2v uv; uv[0] = h_bits(a0); uv[1] = h_bits(a1);
    *(ushort2v*)&u2[n * 4096 + d] = uv;
    ushort2v lv;
    lv[0] = h_bits((_Float16)(u0 - (float)a0));
    lv[1] = h_bits((_Float16)(u1 - (float)a1));
    *(ushort2v*)&u2[n * 4096 + 2048 + d] = lv;
  }
}

__global__ __launch_bounds__(256)
void f1_kernel(const float* __restrict__ x, const float* __restrict__ h,
               unsigned short* __restrict__ r, const float* __restrict__ tbl, int b0) {
  __shared__ float sx[16 * 129];
  const int bl = blockIdx.x, d0 = blockIdx.y * 128, tid = threadIdx.x;
  const float* xb = x + (size_t)(b0 + bl) * 32768;
#pragma unroll
  for (int i = 0; i < 2; i++) {
    int fi = i * 256 + tid, rr = fi >> 2, c = (fi & 3) * 4;
    floatx4 v = *(const floatx4*)&xb[(d0 + rr) * 16 + c];
    sx[(c + 0) * 129 + rr] = v[0];
    sx[(c + 1) * 129 + rr] = v[1];
    sx[(c + 2) * 129 + rr] = v[2];
    sx[(c + 3) * 129 + rr] = v[3];
  }
  __syncthreads();
  const int t4 = tid >> 6, dl = (tid & 63) * 2;
#pragma unroll
  for (int i = 0; i < 4; i++) {
    int t = t4 * 4 + i;
    int d = d0 + dl;
    size_t n = (size_t)bl * 16 + t;
    floatx2 hv = *(const floatx2*)&h[n * 2048 + d];
    float i0 = tbl[d], i1 = tbl[d + 1], q0 = tbl[2048 + d], q1 = tbl[2048 + d + 1];
    float v0 = __fadd_rn(__fadd_rn(__fmul_rn(hv[0], i0), q0), sx[t * 129 + dl]);
    float v1 = __fadd_rn(__fadd_rn(__fmul_rn(hv[1], i1), q1), sx[t * 129 + dl + 1]);
    v0 = fmaxf(v0, 0.f);
    v1 = fmaxf(v1, 0.f);
    ushort2v rv;
    rv[0] = h_bits((_Float16)(v0 * 0x1p-14f));
    rv[1] = h_bits((_Float16)(v1 * 0x1p-14f));
    *(ushort2v*)&r[(size_t)(b0 + bl) * 32768 + (size_t)t * 2048 + d] = rv;
  }
}

__global__ __launch_bounds__(256)
void prep_tbl(const float* __restrict__ g, const float* __restrict__ be,
              const float* __restrict__ me, const float* __restrict__ va,
              float* __restrict__ tbl) {
  int d = blockIdx.x * 256 + threadIdx.x;
  if (d < 2048) {
    float inv = g[d] / sqrtf(va[d] + 1e-5f);
    tbl[d] = inv;
    tbl[2048 + d] = __fsub_rn(be[d], __fmul_rn(me[d], inv));
  }
}

__global__ __launch_bounds__(256)
void prep_qkv(const float* __restrict__ th, const float* __restrict__ ph,
              const float* __restrict__ gw, unsigned short* __restrict__ A1w) {
  int i = (blockIdx.x * 256 + threadIdx.x) * 4;
  int row = i >> 11, d = i & 2047;
  const float* src = (row < 1024) ? (th + (size_t)row * 2048 + d)
                   : (row < 2048) ? (ph + (size_t)(row - 1024) * 2048 + d)
                                  : (gw + (size_t)(row - 2048) * 2048 + d);
  floatx4 v = *(const floatx4*)src;
  ushort4v hi, lo;
#pragma unroll
  for (int j = 0; j < 4; j++) {
    float sc = v[j] * 4096.f;
    _Float16 hh = (_Float16)sc;
    hi[j] = h_bits(hh);
    lo[j] = h_bits((_Float16)(sc - (float)hh));
  }
  size_t base = (size_t)row * 6144 + d;
  *(ushort4v*)&A1w[base] = hi;
  *(ushort4v*)&A1w[base + 2048] = hi;
  *(ushort4v*)&A1w[base + 4096] = lo;
}

__global__ __launch_bounds__(256)
void prep_wc(const float* __restrict__ Ww, unsigned short* __restrict__ Wc6) {
  int i = (blockIdx.x * 256 + threadIdx.x) * 4;
  int row = i >> 10, o = i & 1023;
  floatx4 v = *(const floatx4*)&Ww[(size_t)row * 1024 + o];
  ushort4v hi, lo;
#pragma unroll
  for (int j = 0; j < 4; j++) {
    float sc = v[j] * 4096.f;
    _Float16 hh = (_Float16)sc;
    hi[j] = h_bits(hh);
    lo[j] = h_bits((_Float16)(sc - (float)hh));
  }
  size_t base = (size_t)row * 3072 + o;
  *(ushort4v*)&Wc6[base] = hi;
  *(ushort4v*)&Wc6[base + 1024] = hi;
  *(ushort4v*)&Wc6[base + 2048] = lo;
}

__global__ __launch_bounds__(256)
void prep_w1p(const float* __restrict__ w1, unsigned short* __restrict__ w1p) {
  __shared__ float sx[16 * 129];
  const int oc = blockIdx.x, d0 = blockIdx.y * 128, tid = threadIdx.x;
  const float* wb = w1 + (size_t)oc * 32768;
#pragma unroll
  for (int i = 0; i < 2; i++) {
    int fi = i * 256 + tid, rr = fi >> 2, c = (fi & 3) * 4;
    floatx4 v = *(const floatx4*)&wb[(d0 + rr) * 16 + c];
    sx[(c + 0) * 129 + rr] = v[0];
    sx[(c + 1) * 129 + rr] = v[1];
    sx[(c + 2) * 129 + rr] = v[2];
    sx[(c + 3) * 129 + rr] = v[3];
  }
  __syncthreads();
  const int t4 = tid >> 6, dl = (tid & 63) * 2;
#pragma unroll
  for (int i = 0; i < 4; i++) {
    int t = t4 * 4 + i, d = d0 + dl;
    ushort2v wv;
    wv[0] = h_bits((_Float16)sx[t * 129 + dl]);
    wv[1] = h_bits((_Float16)sx[t * 129 + dl + 1]);
    *(ushort2v*)&w1p[(size_t)oc * 32768 + (size_t)t * 2048 + d] = wv;
  }
}

__global__ __launch_bounds__(256)
void prep_w2t(const float* __restrict__ w2, float* __restrict__ w2t) {
  int o = blockIdx.x, tid = threadIdx.x;
  if (tid < 174) w2t[(size_t)o * 174 + tid] = w2[(size_t)tid * 512 + o];
}

__global__ __launch_bounds__(256)
void fc1red(const float* __restrict__ p, const float* __restrict__ b1,
            float* __restrict__ r1) {
  int i = blockIdx.x * 256 + threadIdx.x;
  int o = i & 511;
  const size_t S = (size_t)2048 * 512;
  float v = p[i] + p[i + S] + p[i + 2 * S] + p[i + 3 * S];
  v = v * 16384.f + b1[o];  // undo r*2^-14 scaling
  r1[i] = fmaxf(v, 0.f);
}

__global__ __launch_bounds__(256)
void fc2_kernel(const float* __restrict__ r1, const float* __restrict__ w2t,
                const float* __restrict__ b2, float* __restrict__ out) {
  __shared__ float sR[512];
  const int b = blockIdx.x, tid = threadIdx.x;
  sR[tid] = r1[(size_t)b * 512 + tid];
  sR[tid + 256] = r1[(size_t)b * 512 + tid + 256];
  __syncthreads();
  if (tid < 174) {
    float a = b2[tid];
    for (int o = 0; o < 512; o++) a += sR[o] * w2t[o * 174 + tid];
    out[(size_t)b * 174 + tid] = a;
  }
}

// ---------------------------------------------------------------------------
extern "C" void kernel_launch(void* const* d_in, const int* in_sizes, int n_in,
                              void* d_out, int out_size, void* d_ws, size_t ws_size,
                              hipStream_t stream) {
  const float* x = (const float*)d_in[0];
  const float* thw = (const float*)d_in[1];
  const float* phw = (const float*)d_in[2];
  const float* gw = (const float*)d_in[3];
  const float* Ww = (const float*)d_in[4];
  const float* gam = (const float*)d_in[5];
  const float* bet = (const float*)d_in[6];
  const float* mea = (const float*)d_in[7];
  const float* var = (const float*)d_in[8];
  const float* w1 = (const float*)d_in[9];
  const float* b1 = (const float*)d_in[10];
  const float* w2 = (const float*)d_in[11];
  const float* b2 = (const float*)d_in[12];

  auto AL = [](size_t v) { return (v + 255) & ~(size_t)255; };
  const size_t fixed = AL((size_t)2048 * 32768 * 2)   // rbuf
                     + AL((size_t)3072 * 6144 * 2)    // A1w
                     + AL((size_t)2048 * 3072 * 2)    // Wc6
                     + AL((size_t)512 * 32768 * 2)    // w1p
                     + AL((size_t)4 * 2048 * 512 * 4) // r1 partials
                     + AL((size_t)2048 * 512 * 4)     // r1
                     + AL((size_t)512 * 174 * 4)      // w2t
                     + AL((size_t)4096 * 4);          // tbl
  int nsplit = 16;
  for (int cand : {1, 2, 4, 8, 16}) {
    size_t Nn_ = (size_t)32768 / cand;
    size_t per = AL(Nn_ * 2048 * 4) + AL(Nn_ * 4096 * 2) +
                 AL((size_t)3072 * Nn_ * 4) + AL(Nn_ * 2048 * 2);
    if (fixed + per <= ws_size) { nsplit = cand; break; }
  }
  const int Nb = 2048 / nsplit;
  const int Nn = Nb * 16;

  char* pp = (char*)d_ws;
  auto take = [&](size_t n) { char* q = pp; pp += (n + 255) & ~(size_t)255; return q; };
  unsigned short* rbuf = (unsigned short*)take((size_t)2048 * 32768 * 2);
  unsigned short* A1w = (unsigned short*)take((size_t)3072 * 6144 * 2);
  unsigned short* Wc6 = (unsigned short*)take((size_t)2048 * 3072 * 2);
  unsigned short* w1p = (unsigned short*)take((size_t)512 * 32768 * 2);
  float* r1p = (float*)take((size_t)4 * 2048 * 512 * 4);
  float* r1 = (float*)take((size_t)2048 * 512 * 4);
  float* w2t = (float*)take((size_t)512 * 174 * 4);
  float* tbl = (float*)take((size_t)4096 * 4);
  float* h = (float*)take((size_t)Nn * 2048 * 4);
  unsigned short* u2 = (unsigned short*)take((size_t)Nn * 4096 * 2);
  float* TPG = (float*)take((size_t)3072 * Nn * 4);
  unsigned short* ctxb = (unsigned short*)take((size_t)Nn * 2048 * 2);

  // per-iteration pow2 scale exponents for u-hat = u * 2^-k  (fp16 range)
  static const int ks[17] = {0, 0, 0, 0, 0, 0, 0, 0, 2, 3, 5, 7, 8, 10, 11, 13, 15};

  prep_tbl<<<8, 256, 0, stream>>>(gam, bet, mea, var, tbl);
  prep_qkv<<<6144, 256, 0, stream>>>(thw, phw, gw, A1w);
  prep_wc<<<2048, 256, 0, stream>>>(Ww, Wc6);
  prep_w1p<<<dim3(512, 16), 256, 0, stream>>>(w1, w1p);
  prep_w2t<<<512, 256, 0, stream>>>(w2, w2t);

  for (int sp = 0; sp < nsplit; sp++) {
    int b0 = sp * Nb;
    e0_kernel<<<dim3(Nb, 16), 256, 0, stream>>>(x, h, u2, tbl, b0, 1.0f);
    for (int it = 0; it < 16; it++) {
      // QKV+G: [3072][6144] x u2 (k-fold at 4096) -> TPG fp32
      gemm_f16<0><<<dim3(24, Nn / 128), 256, 0, stream>>>(
          A1w, 6144, BIGK, u2, 4096, 4096, 6144, TPG, nullptr, Nn, nullptr,
          0.f, 0.f, 0, 0, 0);
      attn_kernel<<<dim3(Nb), 256, 0, stream>>>(
          TPG, ctxb, Nn,
          ldexpf(1.f, 2 * ks[it] - 34),   // score unscale / 1024
          ldexpf(1.f, ks[it] - 12),       // g unscale
          ldexpf(1.f, -ks[it] - 2));      // context scale
      // W-path: ctx (k-fold at 2048) x Wc6 -> h update + next u2
      gemm_f16<2><<<dim3(Nn / 128, 16), 256, 0, stream>>>(
          ctxb, 2048, 2048, Wc6, 3072, BIGK, 3072, h, u2, 2048, tbl,
          ldexpf(1.f, ks[it] - 10),       // ctx unscale
          ldexpf(1.f, -ks[it + 1]),       // next-u scale
          (it < 15) ? 1 : 0, 0, 0);
    }
    f1_kernel<<<dim3(Nb, 16), 256, 0, stream>>>(x, h, rbuf, tbl, b0);
  }

  // fc1: [2048][32768] x [512][32768], split-K over blockIdx.z (4 x 8192)
  gemm_f16<0><<<dim3(16, 4, 4), 256, 0, stream>>>(
      rbuf, 32768, BIGK, w1p, 32768, BIGK, 8192, r1p, nullptr, 512, nullptr,
      0.f, 0.f, 0, 8192, (long)2048 * 512);
  fc1red<<<4096, 256, 0, stream>>>(r1p, b1, r1);
  fc2_kernel<<<2048, 256, 0, stream>>>(r1, w2t, b2, (float*)d_out);
}

// Round 2
// 31625.052 us; speedup vs baseline: 1.1786x; 1.1786x over previous
//
#include <hip/hip_runtime.h>
#include <math.h>
#include <stdint.h>

// ---------------------------------------------------------------------------
// RelationModule on MI355X.
// Layouts (all activations in [n=(b,t)][d] "tbd" order so K is contiguous):
//   h    fp32 [Nn][2048]   : bdt tensor, element (b,d,t) at (b*16+t)*2048+d
//   u2   fp16 [Nn][4096]   : [uh | ul] hi/lo split of u*2^-k (per-iter scale)
//   TPG  fp32 [3072][Nn]   : theta-hat rows 0..1023, phi-hat 1024.., g-hat 2048..
//   ctx  fp16 [Nn][2048]   : [ch | cl] hi/lo split of context*2^(-k-2)
// Weights (fp16, *2^12): A1w [3072][6144] = [Wh|Wh|Wl] per row; Wc6 [2048][3072].
// Precision: 3-term hi/lo fp16 GEMMs (err ~ fp32 accum noise) because the
// softmax is an exact argmax from iter>=3 and any bf16-level score error flips
// selections vs the np reference (catastrophic at 2% absmax threshold).
// R2: XOR chunk swizzle on LDS tiles. Row stride = 32 dwords == 0 mod 32
// banks, so unswizzled fragment reads hit only 4 banks/quad (measured
// SQ_LDS_BANK_CONFLICT 2.27e8/dispatch). Staging source chunk is permuted
// (LDS[m][c] = G[m][c^(m&7)]) since global_load_lds dest is lane-fixed;
// reads use chunk q^(r&7). Bitwise-identical math.
// ---------------------------------------------------------------------------

typedef float  floatx4 __attribute__((ext_vector_type(4)));
typedef float  floatx2 __attribute__((ext_vector_type(2)));
typedef _Float16 half8 __attribute__((ext_vector_type(8)));
typedef short  short8 __attribute__((ext_vector_type(8)));
typedef unsigned short ushort2v __attribute__((ext_vector_type(2)));
typedef unsigned short ushort4v __attribute__((ext_vector_type(4)));

#define BIGK (1 << 28)

__device__ __forceinline__ unsigned short h_bits(_Float16 h) {
  return __builtin_bit_cast(unsigned short, h);
}

__device__ __forceinline__ void gld_lds16(const unsigned short* g, unsigned short* l) {
  __builtin_amdgcn_global_load_lds(
      (const __attribute__((address_space(1))) unsigned int*)g,
      (__attribute__((address_space(3))) unsigned int*)l, 16, 0, 0);
}

// ---------------------------------------------------------------------------
// Generic f16 GEMM, C[m][n] = sum_k A[m][k]*B[n][k]  (both operands k-contig).
// 128x128 tile, BK=64, 4 waves each 64x64 (4x4 MFMA 16x16x32 f16).
// kfA/kfB: k-fold points for the hi/lo 3-term trick (BIGK = disabled).
// EPI 0: plain fp32 store to out0 (ld ldo). (+ optional blockIdx.z K-split)
// EPI 2: residual-block epilogue: out0 = h (ld ldo=2048), out1 = u2 (ld 2*ldo).
// ---------------------------------------------------------------------------
template <int EPI>
__global__ __launch_bounds__(256, 2)
void gemm_f16(const unsigned short* __restrict__ A, int lda, int kfA,
              const unsigned short* __restrict__ B, int ldb, int kfB,
              int K, float* __restrict__ out0, unsigned short* __restrict__ out1,
              int ldo, const float* __restrict__ tbl,
              float cmult, float uscale, int writeU, long zAB, long zO) {
  __shared__ unsigned short As[128 * 64];
  __shared__ unsigned short Bs[128 * 64];
  if (zAB) { A += (long)blockIdx.z * zAB; B += (long)blockIdx.z * zAB; }
  if (zO) { out0 += (long)blockIdx.z * zO; }
  const int tid = threadIdx.x;
  const int w = tid >> 6, l = tid & 63;
  const int quad = l >> 4, lr = l & 15;
  const int m0 = blockIdx.x * 128, n0 = blockIdx.y * 128;
  const int wm = (w & 1) * 64, wn = (w >> 1) * 64;
  const int lsw = lr & 7;  // row&7 for all fragment rows this lane touches

  floatx4 acc[4][4];
#pragma unroll
  for (int a = 0; a < 4; a++)
#pragma unroll
    for (int b = 0; b < 4; b++)
#pragma unroll
      for (int q = 0; q < 4; q++) acc[a][b][q] = 0.f;

  for (int k0 = 0; k0 < K; k0 += 64) {
    int ka = (k0 >= kfA) ? k0 - kfA : k0;
    int kb = (k0 >= kfB) ? k0 - kfB : k0;
    __syncthreads();
#pragma unroll
    for (int i = 0; i < 4; i++) {
      int c = i * 256 + tid;
      int m = c >> 3;
      int kc = ((c & 7) ^ (m & 7)) * 8;  // XOR-swizzled source chunk
      gld_lds16(A + (size_t)(m0 + m) * lda + ka + kc, As + c * 8);
      gld_lds16(B + (size_t)(n0 + m) * ldb + kb + kc, Bs + c * 8);
    }
    __syncthreads();
#pragma unroll
    for (int kk = 0; kk < 64; kk += 32) {
      const int kq = (kk >> 3) + quad;  // k-chunk index 0..7
      const int ksw = (kq ^ lsw) * 8;   // swizzled LDS chunk offset
      short8 af[4], bf[4];
#pragma unroll
      for (int mi = 0; mi < 4; mi++)
        af[mi] = *(const short8*)(As + (wm + mi * 16 + lr) * 64 + ksw);
#pragma unroll
      for (int ni = 0; ni < 4; ni++)
        bf[ni] = *(const short8*)(Bs + (wn + ni * 16 + lr) * 64 + ksw);
#pragma unroll
      for (int mi = 0; mi < 4; mi++)
#pragma unroll
        for (int ni = 0; ni < 4; ni++)
          acc[mi][ni] = __builtin_amdgcn_mfma_f32_16x16x32_f16(
              __builtin_bit_cast(half8, af[mi]),
              __builtin_bit_cast(half8, bf[ni]), acc[mi][ni], 0, 0, 0);
    }
  }

  if (EPI == 0) {
#pragma unroll
    for (int mi = 0; mi < 4; mi++)
#pragma unroll
      for (int i2 = 0; i2 < 4; i2++) {
        int row = m0 + wm + mi * 16 + quad * 4 + i2;
#pragma unroll
        for (int ni = 0; ni < 4; ni++) {
          int col = n0 + wn + ni * 16 + lr;
          out0[(size_t)row * ldo + col] = acc[mi][ni][i2];
        }
      }
  } else {
    // EPI 2: rows = n (b,t), cols = d.  Replicate np's elementwise op order.
    float invv[4], bb[4];
#pragma unroll
    for (int ni = 0; ni < 4; ni++) {
      int d = n0 + wn + ni * 16 + lr;
      invv[ni] = tbl[d];
      bb[ni] = tbl[2048 + d];
    }
#pragma unroll
    for (int mi = 0; mi < 4; mi++)
#pragma unroll
      for (int i2 = 0; i2 < 4; i2++) {
        size_t row = (size_t)(m0 + wm + mi * 16 + quad * 4 + i2);
#pragma unroll
        for (int ni = 0; ni < 4; ni++) {
          int d = n0 + wn + ni * 16 + lr;
          size_t off = row * (size_t)ldo + d;
          float hold = out0[off];
          float ctxv = acc[mi][ni][i2] * cmult;  // true-scale W@context
          float u = __fadd_rn(__fmul_rn(hold, invv[ni]), bb[ni]);   // bn(h)
          float cb = __fadd_rn(__fmul_rn(ctxv, invv[ni]), bb[ni]);  // bn(ctx)
          float o1 = __fadd_rn(cb, u);
          float h2 = __fadd_rn(__fmul_rn(o1, invv[ni]), bb[ni]);    // bn(o1)
          float hn = __fadd_rn(h2, hold);                           // + residual
          out0[off] = hn;
          float un = __fadd_rn(__fmul_rn(hn, invv[ni]), bb[ni]);    // next u
          acc[mi][ni][i2] = un * uscale;
        }
      }
    if (writeU) {
      // LDS-stage u-hi then u-lo for coalesced 16B fp16 stores.
      unsigned short* st = (w < 2) ? (As + w * 4096) : (Bs + (w - 2) * 4096);
      __syncthreads();
#pragma unroll
      for (int mi = 0; mi < 4; mi++)
#pragma unroll
        for (int i2 = 0; i2 < 4; i2++) {
          int rr = mi * 16 + quad * 4 + i2;
#pragma unroll
          for (int ni = 0; ni < 4; ni++)
            st[rr * 64 + ni * 16 + lr] = h_bits((_Float16)acc[mi][ni][i2]);
        }
      __syncthreads();
#pragma unroll
      for (int j = 0; j < 8; j++) {
        int chk = j * 64 + l, rr = chk >> 3, c8 = (chk & 7) * 8;
        short8 v = *(const short8*)(st + rr * 64 + c8);
        *(short8*)(out1 + (size_t)(m0 + wm + rr) * (2 * ldo) + n0 + wn + c8) = v;
      }
      __syncthreads();
#pragma unroll
      for (int mi = 0; mi < 4; mi++)
#pragma unroll
        for (int i2 = 0; i2 < 4; i2++) {
          int rr = mi * 16 + quad * 4 + i2;
#pragma unroll
          for (int ni = 0; ni < 4; ni++) {
            float u = acc[mi][ni][i2];
            _Float16 hh = (_Float16)u;
            st[rr * 64 + ni * 16 + lr] = h_bits((_Float16)(u - (float)hh));
          }
        }
      __syncthreads();
#pragma unroll
      for (int j = 0; j < 8; j++) {
        int chk = j * 64 + l, rr = chk >> 3, c8 = (chk & 7) * 8;
        short8 v = *(const short8*)(st + rr * 64 + c8);
        *(short8*)(out1 + (size_t)(m0 + wm + rr) * (2 * ldo) + ldo + n0 + wn + c8) = v;
      }
    }
  }
}

// ---------------------------------------------------------------------------
// Attention per b: scores (fp64 acc) -> softmax -> context, hi/lo fp16 out.
// ---------------------------------------------------------------------------
__global__ __launch_bounds__(256)
void attn_kernel(const float* __restrict__ TPG, unsigned short* __restrict__ ctx,
                 int Nn, float smult, float gmult, float scmult) {
  __shared__ float sTh[128 * 16];
  __shared__ float sPh[128 * 16];
  __shared__ float sGc[128 * 17];
  __shared__ float sS[256];
  __shared__ float sA[256];
  const int b = blockIdx.x, tid = threadIdx.x;
  const int t = tid >> 4, s = tid & 15;
  double acc = 0.0;
  for (int cc = 0; cc < 8; cc++) {
#pragma unroll
    for (int i = 0; i < 2; i++) {
      int fi = i * 256 + tid, r = fi >> 2, c = (fi & 3) * 4;
      *(floatx4*)&sTh[r * 16 + c] =
          *(const floatx4*)&TPG[(size_t)(cc * 128 + r) * Nn + b * 16 + c];
      *(floatx4*)&sPh[r * 16 + c] =
          *(const floatx4*)&TPG[(size_t)(1024 + cc * 128 + r) * Nn + b * 16 + c];
    }
    __syncthreads();
    for (int o = 0; o < 128; o++)
      acc += (double)sTh[o * 16 + t] * (double)sPh[o * 16 + s];
    __syncthreads();
  }
  float sv = (float)(acc * (double)smult);
  sS[tid] = sv;
  __syncthreads();
  float mx = sS[t * 16];
#pragma unroll
  for (int j = 1; j < 16; j++) mx = fmaxf(mx, sS[t * 16 + j]);
  float e = expf(sv - mx);
  sA[tid] = e;
  __syncthreads();
  float sum = 0.f;
#pragma unroll
  for (int j = 0; j < 16; j++) sum += sA[t * 16 + j];
  float alpha = e / sum;
  __syncthreads();
  sA[tid] = alpha;
  __syncthreads();
  const int t2 = tid >> 7, ol = tid & 127;
  for (int cc = 0; cc < 8; cc++) {
#pragma unroll
    for (int i = 0; i < 2; i++) {
      int fi = i * 256 + tid, r = fi >> 2, c = (fi & 3) * 4;
      floatx4 g = *(const floatx4*)&TPG[(size_t)(2048 + cc * 128 + r) * Nn + b * 16 + c];
      sGc[r * 17 + c + 0] = g[0] * gmult;
      sGc[r * 17 + c + 1] = g[1] * gmult;
      sGc[r * 17 + c + 2] = g[2] * gmult;
      sGc[r * 17 + c + 3] = g[3] * gmult;
    }
    __syncthreads();
#pragma unroll
    for (int tt = 0; tt < 8; tt++) {
      int tc = t2 + tt * 2;
      float cv = 0.f;
#pragma unroll
      for (int s2 = 0; s2 < 16; s2++) cv += sA[tc * 16 + s2] * sGc[ol * 17 + s2];
      float cs = cv * scmult;
      _Float16 chh = (_Float16)cs;
      _Float16 cll = (_Float16)(cs - (float)chh);
      size_t base = ((size_t)b * 16 + tc) * 2048 + cc * 128 + ol;
      ctx[base] = h_bits(chh);
      ctx[base + 1024] = h_bits(cll);
    }
    __syncthreads();
  }
}

// ---------------------------------------------------------------------------
// Elementwise / transpose / prep kernels
// ---------------------------------------------------------------------------
__global__ __launch_bounds__(256)
void e0_kernel(const float* __restrict__ x, float* __restrict__ h,
               unsigned short* __restrict__ u2, const float* __restrict__ tbl,
               int b0, float uscale) {
  __shared__ float sx[16 * 129];
  const int bl = blockIdx.x, d0 = blockIdx.y * 128, tid = threadIdx.x;
  const float* xb = x + (size_t)(b0 + bl) * 32768;
#pragma unroll
  for (int i = 0; i < 2; i++) {
    int fi = i * 256 + tid, r = fi >> 2, c = (fi & 3) * 4;
    floatx4 v = *(const floatx4*)&xb[(d0 + r) * 16 + c];
    sx[(c + 0) * 129 + r] = v[0];
    sx[(c + 1) * 129 + r] = v[1];
    sx[(c + 2) * 129 + r] = v[2];
    sx[(c + 3) * 129 + r] = v[3];
  }
  __syncthreads();
  const int t4 = tid >> 6, dl = (tid & 63) * 2;
#pragma unroll
  for (int i = 0; i < 4; i++) {
    int t = t4 * 4 + i;
    int d = d0 + dl;
    float x0 = sx[t * 129 + dl], x1 = sx[t * 129 + dl + 1];
    size_t n = (size_t)bl * 16 + t;
    floatx2 hv; hv[0] = x0; hv[1] = x1;
    *(floatx2*)&h[n * 2048 + d] = hv;
    float i0 = tbl[d], i1 = tbl[d + 1], q0 = tbl[2048 + d], q1 = tbl[2048 + d + 1];
    float u0 = __fadd_rn(__fmul_rn(x0, i0), q0) * uscale;
    float u1 = __fadd_rn(__fmul_rn(x1, i1), q1) * uscale;
    _Float16 a0 = (_Float16)u0, a1 = (_Float16)u1;
    ushort2v uv; uv[0] = h_bits(a0); uv[1] = h_bits(a1);
    *(ushort2v*)&u2[n * 4096 + d] = uv;
    ushort2v lv;
    lv[0] = h_bits((_Float16)(u0 - (float)a0));
    lv[1] = h_bits((_Float16)(u1 - (float)a1));
    *(ushort2v*)&u2[n * 4096 + 2048 + d] = lv;
  }
}

__global__ __launch_bounds__(256)
void f1_kernel(const float* __restrict__ x, const float* __restrict__ h,
               unsigned short* __restrict__ r, const float* __restrict__ tbl, int b0) {
  __shared__ float sx[16 * 129];
  const int bl = blockIdx.x, d0 = blockIdx.y * 128, tid = threadIdx.x;
  const float* xb = x + (size_t)(b0 + bl) * 32768;
#pragma unroll
  for (int i = 0; i < 2; i++) {
    int fi = i * 256 + tid, rr = fi >> 2, c = (fi & 3) * 4;
    floatx4 v = *(const floatx4*)&xb[(d0 + rr) * 16 + c];
    sx[(c + 0) * 129 + rr] = v[0];
    sx[(c + 1) * 129 + rr] = v[1];
    sx[(c + 2) * 129 + rr] = v[2];
    sx[(c + 3) * 129 + rr] = v[3];
  }
  __syncthreads();
  const int t4 = tid >> 6, dl = (tid & 63) * 2;
#pragma unroll
  for (int i = 0; i < 4; i++) {
    int t = t4 * 4 + i;
    int d = d0 + dl;
    size_t n = (size_t)bl * 16 + t;
    floatx2 hv = *(const floatx2*)&h[n * 2048 + d];
    float i0 = tbl[d], i1 = tbl[d + 1], q0 = tbl[2048 + d], q1 = tbl[2048 + d + 1];
    float v0 = __fadd_rn(__fadd_rn(__fmul_rn(hv[0], i0), q0), sx[t * 129 + dl]);
    float v1 = __fadd_rn(__fadd_rn(__fmul_rn(hv[1], i1), q1), sx[t * 129 + dl + 1]);
    v0 = fmaxf(v0, 0.f);
    v1 = fmaxf(v1, 0.f);
    ushort2v rv;
    rv[0] = h_bits((_Float16)(v0 * 0x1p-14f));
    rv[1] = h_bits((_Float16)(v1 * 0x1p-14f));
    *(ushort2v*)&r[(size_t)(b0 + bl) * 32768 + (size_t)t * 2048 + d] = rv;
  }
}

__global__ __launch_bounds__(256)
void prep_tbl(const float* __restrict__ g, const float* __restrict__ be,
              const float* __restrict__ me, const float* __restrict__ va,
              float* __restrict__ tbl) {
  int d = blockIdx.x * 256 + threadIdx.x;
  if (d < 2048) {
    float inv = g[d] / sqrtf(va[d] + 1e-5f);
    tbl[d] = inv;
    tbl[2048 + d] = __fsub_rn(be[d], __fmul_rn(me[d], inv));
  }
}

__global__ __launch_bounds__(256)
void prep_qkv(const float* __restrict__ th, const float* __restrict__ ph,
              const float* __restrict__ gw, unsigned short* __restrict__ A1w) {
  int i = (blockIdx.x * 256 + threadIdx.x) * 4;
  int row = i >> 11, d = i & 2047;
  const float* src = (row < 1024) ? (th + (size_t)row * 2048 + d)
                   : (row < 2048) ? (ph + (size_t)(row - 1024) * 2048 + d)
                                  : (gw + (size_t)(row - 2048) * 2048 + d);
  floatx4 v = *(const floatx4*)src;
  ushort4v hi, lo;
#pragma unroll
  for (int j = 0; j < 4; j++) {
    float sc = v[j] * 4096.f;
    _Float16 hh = (_Float16)sc;
    hi[j] = h_bits(hh);
    lo[j] = h_bits((_Float16)(sc - (float)hh));
  }
  size_t base = (size_t)row * 6144 + d;
  *(ushort4v*)&A1w[base] = hi;
  *(ushort4v*)&A1w[base + 2048] = hi;
  *(ushort4v*)&A1w[base + 4096] = lo;
}

__global__ __launch_bounds__(256)
void prep_wc(const float* __restrict__ Ww, unsigned short* __restrict__ Wc6) {
  int i = (blockIdx.x * 256 + threadIdx.x) * 4;
  int row = i >> 10, o = i & 1023;
  floatx4 v = *(const floatx4*)&Ww[(size_t)row * 1024 + o];
  ushort4v hi, lo;
#pragma unroll
  for (int j = 0; j < 4; j++) {
    float sc = v[j] * 4096.f;
    _Float16 hh = (_Float16)sc;
    hi[j] = h_bits(hh);
    lo[j] = h_bits((_Float16)(sc - (float)hh));
  }
  size_t base = (size_t)row * 3072 + o;
  *(ushort4v*)&Wc6[base] = hi;
  *(ushort4v*)&Wc6[base + 1024] = hi;
  *(ushort4v*)&Wc6[base + 2048] = lo;
}

__global__ __launch_bounds__(256)
void prep_w1p(const float* __restrict__ w1, unsigned short* __restrict__ w1p) {
  __shared__ float sx[16 * 129];
  const int oc = blockIdx.x, d0 = blockIdx.y * 128, tid = threadIdx.x;
  const float* wb = w1 + (size_t)oc * 32768;
#pragma unroll
  for (int i = 0; i < 2; i++) {
    int fi = i * 256 + tid, rr = fi >> 2, c = (fi & 3) * 4;
    floatx4 v = *(const floatx4*)&wb[(d0 + rr) * 16 + c];
    sx[(c + 0) * 129 + rr] = v[0];
    sx[(c + 1) * 129 + rr] = v[1];
    sx[(c + 2) * 129 + rr] = v[2];
    sx[(c + 3) * 129 + rr] = v[3];
  }
  __syncthreads();
  const int t4 = tid >> 6, dl = (tid & 63) * 2;
#pragma unroll
  for (int i = 0; i < 4; i++) {
    int t = t4 * 4 + i, d = d0 + dl;
    ushort2v wv;
    wv[0] = h_bits((_Float16)sx[t * 129 + dl]);
    wv[1] = h_bits((_Float16)sx[t * 129 + dl + 1]);
    *(ushort2v*)&w1p[(size_t)oc * 32768 + (size_t)t * 2048 + d] = wv;
  }
}

__global__ __launch_bounds__(256)
void prep_w2t(const float* __restrict__ w2, float* __restrict__ w2t) {
  int o = blockIdx.x, tid = threadIdx.x;
  if (tid < 174) w2t[(size_t)o * 174 + tid] = w2[(size_t)tid * 512 + o];
}

__global__ __launch_bounds__(256)
void fc1red(const float* __restrict__ p, const float* __restrict__ b1,
            float* __restrict__ r1) {
  int i = blockIdx.x * 256 + threadIdx.x;
  int o = i & 511;
  const size_t S = (size_t)2048 * 512;
  float v = p[i] + p[i + S] + p[i + 2 * S] + p[i + 3 * S];
  v = v * 16384.f + b1[o];  // undo r*2^-14 scaling
  r1[i] = fmaxf(v, 0.f);
}

__global__ __launch_bounds__(256)
void fc2_kernel(const float* __restrict__ r1, const float* __restrict__ w2t,
                const float* __restrict__ b2, float* __restrict__ out) {
  __shared__ float sR[512];
  const int b = blockIdx.x, tid = threadIdx.x;
  sR[tid] = r1[(size_t)b * 512 + tid];
  sR[tid + 256] = r1[(size_t)b * 512 + tid + 256];
  __syncthreads();
  if (tid < 174) {
    float a = b2[tid];
    for (int o = 0; o < 512; o++) a += sR[o] * w2t[o * 174 + tid];
    out[(size_t)b * 174 + tid] = a;
  }
}

// ---------------------------------------------------------------------------
extern "C" void kernel_launch(void* const* d_in, const int* in_sizes, int n_in,
                              void* d_out, int out_size, void* d_ws, size_t ws_size,
                              hipStream_t stream) {
  const float* x = (const float*)d_in[0];
  const float* thw = (const float*)d_in[1];
  const float* phw = (const float*)d_in[2];
  const float* gw = (const float*)d_in[3];
  const float* Ww = (const float*)d_in[4];
  const float* gam = (const float*)d_in[5];
  const float* bet = (const float*)d_in[6];
  const float* mea = (const float*)d_in[7];
  const float* var = (const float*)d_in[8];
  const float* w1 = (const float*)d_in[9];
  const float* b1 = (const float*)d_in[10];
  const float* w2 = (const float*)d_in[11];
  const float* b2 = (const float*)d_in[12];

  auto AL = [](size_t v) { return (v + 255) & ~(size_t)255; };
  const size_t fixed = AL((size_t)2048 * 32768 * 2)   // rbuf
                     + AL((size_t)3072 * 6144 * 2)    // A1w
                     + AL((size_t)2048 * 3072 * 2)    // Wc6
                     + AL((size_t)512 * 32768 * 2)    // w1p
                     + AL((size_t)4 * 2048 * 512 * 4) // r1 partials
                     + AL((size_t)2048 * 512 * 4)     // r1
                     + AL((size_t)512 * 174 * 4)      // w2t
                     + AL((size_t)4096 * 4);          // tbl
  int nsplit = 16;
  for (int cand : {1, 2, 4, 8, 16}) {
    size_t Nn_ = (size_t)32768 / cand;
    size_t per = AL(Nn_ * 2048 * 4) + AL(Nn_ * 4096 * 2) +
                 AL((size_t)3072 * Nn_ * 4) + AL(Nn_ * 2048 * 2);
    if (fixed + per <= ws_size) { nsplit = cand; break; }
  }
  const int Nb = 2048 / nsplit;
  const int Nn = Nb * 16;

  char* pp = (char*)d_ws;
  auto take = [&](size_t n) { char* q = pp; pp += (n + 255) & ~(size_t)255; return q; };
  unsigned short* rbuf = (unsigned short*)take((size_t)2048 * 32768 * 2);
  unsigned short* A1w = (unsigned short*)take((size_t)3072 * 6144 * 2);
  unsigned short* Wc6 = (unsigned short*)take((size_t)2048 * 3072 * 2);
  unsigned short* w1p = (unsigned short*)take((size_t)512 * 32768 * 2);
  float* r1p = (float*)take((size_t)4 * 2048 * 512 * 4);
  float* r1 = (float*)take((size_t)2048 * 512 * 4);
  float* w2t = (float*)take((size_t)512 * 174 * 4);
  float* tbl = (float*)take((size_t)4096 * 4);
  float* h = (float*)take((size_t)Nn * 2048 * 4);
  unsigned short* u2 = (unsigned short*)take((size_t)Nn * 4096 * 2);
  float* TPG = (float*)take((size_t)3072 * Nn * 4);
  unsigned short* ctxb = (unsigned short*)take((size_t)Nn * 2048 * 2);

  // per-iteration pow2 scale exponents for u-hat = u * 2^-k  (fp16 range)
  static const int ks[17] = {0, 0, 0, 0, 0, 0, 0, 0, 2, 3, 5, 7, 8, 10, 11, 13, 15};

  prep_tbl<<<8, 256, 0, stream>>>(gam, bet, mea, var, tbl);
  prep_qkv<<<6144, 256, 0, stream>>>(thw, phw, gw, A1w);
  prep_wc<<<2048, 256, 0, stream>>>(Ww, Wc6);
  prep_w1p<<<dim3(512, 16), 256, 0, stream>>>(w1, w1p);
  prep_w2t<<<512, 256, 0, stream>>>(w2, w2t);

  for (int sp = 0; sp < nsplit; sp++) {
    int b0 = sp * Nb;
    e0_kernel<<<dim3(Nb, 16), 256, 0, stream>>>(x, h, u2, tbl, b0, 1.0f);
    for (int it = 0; it < 16; it++) {
      // QKV+G: [3072][6144] x u2 (k-fold at 4096) -> TPG fp32
      gemm_f16<0><<<dim3(24, Nn / 128), 256, 0, stream>>>(
          A1w, 6144, BIGK, u2, 4096, 4096, 6144, TPG, nullptr, Nn, nullptr,
          0.f, 0.f, 0, 0, 0);
      attn_kernel<<<dim3(Nb), 256, 0, stream>>>(
          TPG, ctxb, Nn,
          ldexpf(1.f, 2 * ks[it] - 34),   // score unscale / 1024
          ldexpf(1.f, ks[it] - 12),       // g unscale
          ldexpf(1.f, -ks[it] - 2));      // context scale
      // W-path: ctx (k-fold at 2048) x Wc6 -> h update + next u2
      gemm_f16<2><<<dim3(Nn / 128, 16), 256, 0, stream>>>(
          ctxb, 2048, 2048, Wc6, 3072, BIGK, 3072, h, u2, 2048, tbl,
          ldexpf(1.f, ks[it] - 10),       // ctx unscale
          ldexpf(1.f, -ks[it + 1]),       // next-u scale
          (it < 15) ? 1 : 0, 0, 0);
    }
    f1_kernel<<<dim3(Nb, 16), 256, 0, stream>>>(x, h, rbuf, tbl, b0);
  }

  // fc1: [2048][32768] x [512][32768], split-K over blockIdx.z (4 x 8192)
  gemm_f16<0><<<dim3(16, 4, 4), 256, 0, stream>>>(
      rbuf, 32768, BIGK, w1p, 32768, BIGK, 8192, r1p, nullptr, 512, nullptr,
      0.f, 0.f, 0, 8192, (long)2048 * 512);
  fc1red<<<4096, 256, 0, stream>>>(r1p, b1, r1);
  fc2_kernel<<<2048, 256, 0, stream>>>(r1, w2t, b2, (float*)d_out);
}

// Round 3
// 31011.090 us; speedup vs baseline: 1.2019x; 1.0198x over previous
//
#include <hip/hip_runtime.h>
#include <math.h>
#include <stdint.h>

// ---------------------------------------------------------------------------
// RelationModule on MI355X.
// Layouts (all activations in [n=(b,t)][d] "tbd" order so K is contiguous):
//   h    fp32 [Nn][2048]   : bdt tensor, element (b,d,t) at (b*16+t)*2048+d
//   u2   fp16 [Nn][4096]   : [uh | ul] hi/lo split of u*2^-k (per-iter scale)
//   TPG  fp32 [3072][Nn]   : theta-hat rows 0..1023, phi-hat 1024.., g-hat 2048..
//   ctx  fp16 [Nn][2048]   : [ch | cl] hi/lo split of context*2^(-k-2)
// Weights (fp16, *2^12): A1w [3072][4096] = [Wh|Wl]; Wc2 [2048][2048] = [Wh|Wl].
// Precision: 3-product hi/lo fp16 GEMMs (AhBh+AhBl+AlBh, err ~ fp32 accum
// noise) because the softmax is an exact argmax from iter>=3 and any
// bf16-level score error flips selections vs the np reference.
// R2: XOR chunk swizzle -> SQ_LDS_BANK_CONFLICT 2.27e8 -> 0.
// R3: 4-panel K-loop (BK=32, Ah/Al/Bh/Bl staged once, 3 products from
// register fragments) replaces the 6-panel [Wh|Wh|Wl]x[uh|ul|uh] stream:
// -33% LDS traffic, -33% barriers, same MFMA count. LDS was the binding
// pipe (~60% busy vs MfmaUtil 47.7%).
// ---------------------------------------------------------------------------

typedef float  floatx4 __attribute__((ext_vector_type(4)));
typedef float  floatx2 __attribute__((ext_vector_type(2)));
typedef _Float16 half8 __attribute__((ext_vector_type(8)));
typedef short  short8 __attribute__((ext_vector_type(8)));
typedef unsigned short ushort2v __attribute__((ext_vector_type(2)));
typedef unsigned short ushort4v __attribute__((ext_vector_type(4)));

__device__ __forceinline__ unsigned short h_bits(_Float16 h) {
  return __builtin_bit_cast(unsigned short, h);
}

__device__ __forceinline__ void gld_lds16(const unsigned short* g, unsigned short* l) {
  __builtin_amdgcn_global_load_lds(
      (const __attribute__((address_space(1))) unsigned int*)g,
      (__attribute__((address_space(3))) unsigned int*)l, 16, 0, 0);
}

#define MFMA16(a, b, c) \
  __builtin_amdgcn_mfma_f32_16x16x32_f16( \
      __builtin_bit_cast(half8, a), __builtin_bit_cast(half8, b), c, 0, 0, 0)

// ---------------------------------------------------------------------------
// f16 GEMM, C[m][n] = sum_k A[m][k]*B[n][k] (both k-contiguous).
// 128x128 tile, 4 waves each 64x64 (4x4 of 16x16x32 f16 MFMA).
// TERMS==3: A/B are hi|lo pairs (hi at col 0, lo at col K2); BK=32, four
//   panels staged per phase, products AhBh+AhBl+AlBh.
// TERMS==1: plain f16, BK=64 (fc1 path).
// EPI 0: fp32 store to out0 (+ optional blockIdx.z K/out split).
// EPI 2: residual-block epilogue: out0 = h (ldo=2048), out1 = u2 (2*ldo).
// ---------------------------------------------------------------------------
template <int TERMS, int EPI>
__global__ __launch_bounds__(256, 2)
void gemm_f16(const unsigned short* __restrict__ A, int lda,
              const unsigned short* __restrict__ B, int ldb,
              int K2, float* __restrict__ out0, unsigned short* __restrict__ out1,
              int ldo, const float* __restrict__ tbl,
              float cmult, float uscale, int writeU, long zAB, long zO) {
  __shared__ unsigned short sm[4][128 * 32];
  if (zAB) { A += (long)blockIdx.z * zAB; B += (long)blockIdx.z * zAB; }
  if (zO) { out0 += (long)blockIdx.z * zO; }
  const int tid = threadIdx.x;
  const int w = tid >> 6, l = tid & 63;
  const int quad = l >> 4, lr = l & 15;
  const int m0 = blockIdx.x * 128, n0 = blockIdx.y * 128;
  const int wm = (w & 1) * 64, wn = (w >> 1) * 64;

  floatx4 acc[4][4];
#pragma unroll
  for (int a = 0; a < 4; a++)
#pragma unroll
    for (int b = 0; b < 4; b++)
#pragma unroll
      for (int q = 0; q < 4; q++) acc[a][b][q] = 0.f;

  if (TERMS == 3) {
    const unsigned short* Alo = A + K2;
    const unsigned short* Blo = B + K2;
    const int fsw = (quad ^ ((lr >> 1) & 3)) * 8;
    for (int k0 = 0; k0 < K2; k0 += 32) {
      __syncthreads();
#pragma unroll
      for (int i = 0; i < 2; i++) {
        int c = i * 256 + tid;
        int m = c >> 2;
        int cs = ((c & 3) ^ ((m >> 1) & 3)) * 8;
        gld_lds16(A + (size_t)(m0 + m) * lda + k0 + cs, &sm[0][0] + c * 8);
        gld_lds16(Alo + (size_t)(m0 + m) * lda + k0 + cs, &sm[1][0] + c * 8);
        gld_lds16(B + (size_t)(n0 + m) * ldb + k0 + cs, &sm[2][0] + c * 8);
        gld_lds16(Blo + (size_t)(n0 + m) * ldb + k0 + cs, &sm[3][0] + c * 8);
      }
      __syncthreads();
      short8 ah[4], bh[4], al[4], bl[4];
#pragma unroll
      for (int mi = 0; mi < 4; mi++) {
        ah[mi] = *(const short8*)(&sm[0][0] + (wm + mi * 16 + lr) * 32 + fsw);
        al[mi] = *(const short8*)(&sm[1][0] + (wm + mi * 16 + lr) * 32 + fsw);
      }
#pragma unroll
      for (int ni = 0; ni < 4; ni++) {
        bh[ni] = *(const short8*)(&sm[2][0] + (wn + ni * 16 + lr) * 32 + fsw);
        bl[ni] = *(const short8*)(&sm[3][0] + (wn + ni * 16 + lr) * 32 + fsw);
      }
#pragma unroll
      for (int mi = 0; mi < 4; mi++)
#pragma unroll
        for (int ni = 0; ni < 4; ni++)
          acc[mi][ni] = MFMA16(ah[mi], bh[ni], acc[mi][ni]);
#pragma unroll
      for (int mi = 0; mi < 4; mi++)
#pragma unroll
        for (int ni = 0; ni < 4; ni++)
          acc[mi][ni] = MFMA16(ah[mi], bl[ni], acc[mi][ni]);
#pragma unroll
      for (int mi = 0; mi < 4; mi++)
#pragma unroll
        for (int ni = 0; ni < 4; ni++)
          acc[mi][ni] = MFMA16(al[mi], bh[ni], acc[mi][ni]);
    }
  } else {
    // Plain f16, BK=64; As = sm[0..1], Bs = sm[2..3].
    unsigned short* As = &sm[0][0];
    unsigned short* Bs = &sm[2][0];
    const int lsw = lr & 7;
    for (int k0 = 0; k0 < K2; k0 += 64) {
      __syncthreads();
#pragma unroll
      for (int i = 0; i < 4; i++) {
        int c = i * 256 + tid;
        int m = c >> 3;
        int kc = ((c & 7) ^ (m & 7)) * 8;
        gld_lds16(A + (size_t)(m0 + m) * lda + k0 + kc, As + c * 8);
        gld_lds16(B + (size_t)(n0 + m) * ldb + k0 + kc, Bs + c * 8);
      }
      __syncthreads();
#pragma unroll
      for (int kk = 0; kk < 64; kk += 32) {
        const int kq = (kk >> 3) + quad;
        const int ksw = (kq ^ lsw) * 8;
        short8 af[4], bf[4];
#pragma unroll
        for (int mi = 0; mi < 4; mi++)
          af[mi] = *(const short8*)(As + (wm + mi * 16 + lr) * 64 + ksw);
#pragma unroll
        for (int ni = 0; ni < 4; ni++)
          bf[ni] = *(const short8*)(Bs + (wn + ni * 16 + lr) * 64 + ksw);
#pragma unroll
        for (int mi = 0; mi < 4; mi++)
#pragma unroll
          for (int ni = 0; ni < 4; ni++)
            acc[mi][ni] = MFMA16(af[mi], bf[ni], acc[mi][ni]);
      }
    }
  }

  if (EPI == 0) {
#pragma unroll
    for (int mi = 0; mi < 4; mi++)
#pragma unroll
      for (int i2 = 0; i2 < 4; i2++) {
        int row = m0 + wm + mi * 16 + quad * 4 + i2;
#pragma unroll
        for (int ni = 0; ni < 4; ni++) {
          int col = n0 + wn + ni * 16 + lr;
          out0[(size_t)row * ldo + col] = acc[mi][ni][i2];
        }
      }
  } else {
    // EPI 2: rows = n (b,t), cols = d.  Replicate np's elementwise op order.
    float invv[4], bb[4];
#pragma unroll
    for (int ni = 0; ni < 4; ni++) {
      int d = n0 + wn + ni * 16 + lr;
      invv[ni] = tbl[d];
      bb[ni] = tbl[2048 + d];
    }
#pragma unroll
    for (int mi = 0; mi < 4; mi++)
#pragma unroll
      for (int i2 = 0; i2 < 4; i2++) {
        size_t row = (size_t)(m0 + wm + mi * 16 + quad * 4 + i2);
#pragma unroll
        for (int ni = 0; ni < 4; ni++) {
          int d = n0 + wn + ni * 16 + lr;
          size_t off = row * (size_t)ldo + d;
          float hold = out0[off];
          float ctxv = acc[mi][ni][i2] * cmult;  // true-scale W@context
          float u = __fadd_rn(__fmul_rn(hold, invv[ni]), bb[ni]);   // bn(h)
          float cb = __fadd_rn(__fmul_rn(ctxv, invv[ni]), bb[ni]);  // bn(ctx)
          float o1 = __fadd_rn(cb, u);
          float h2 = __fadd_rn(__fmul_rn(o1, invv[ni]), bb[ni]);    // bn(o1)
          float hn = __fadd_rn(h2, hold);                           // + residual
          out0[off] = hn;
          float un = __fadd_rn(__fmul_rn(hn, invv[ni]), bb[ni]);    // next u
          acc[mi][ni][i2] = un * uscale;
        }
      }
    if (writeU) {
      // LDS-stage u-hi then u-lo for coalesced 16B fp16 stores.
      unsigned short* st = &sm[w][0];
      __syncthreads();
#pragma unroll
      for (int mi = 0; mi < 4; mi++)
#pragma unroll
        for (int i2 = 0; i2 < 4; i2++) {
          int rr = mi * 16 + quad * 4 + i2;
#pragma unroll
          for (int ni = 0; ni < 4; ni++)
            st[rr * 64 + ni * 16 + lr] = h_bits((_Float16)acc[mi][ni][i2]);
        }
      __syncthreads();
#pragma unroll
      for (int j = 0; j < 8; j++) {
        int chk = j * 64 + l, rr = chk >> 3, c8 = (chk & 7) * 8;
        short8 v = *(const short8*)(st + rr * 64 + c8);
        *(short8*)(out1 + (size_t)(m0 + wm + rr) * (2 * ldo) + n0 + wn + c8) = v;
      }
      __syncthreads();
#pragma unroll
      for (int mi = 0; mi < 4; mi++)
#pragma unroll
        for (int i2 = 0; i2 < 4; i2++) {
          int rr = mi * 16 + quad * 4 + i2;
#pragma unroll
          for (int ni = 0; ni < 4; ni++) {
            float u = acc[mi][ni][i2];
            _Float16 hh = (_Float16)u;
            st[rr * 64 + ni * 16 + lr] = h_bits((_Float16)(u - (float)hh));
          }
        }
      __syncthreads();
#pragma unroll
      for (int j = 0; j < 8; j++) {
        int chk = j * 64 + l, rr = chk >> 3, c8 = (chk & 7) * 8;
        short8 v = *(const short8*)(st + rr * 64 + c8);
        *(short8*)(out1 + (size_t)(m0 + wm + rr) * (2 * ldo) + ldo + n0 + wn + c8) = v;
      }
    }
  }
}

// ---------------------------------------------------------------------------
// Attention per b: scores (fp64 acc) -> softmax -> context, hi/lo fp16 out.
// ---------------------------------------------------------------------------
__global__ __launch_bounds__(256)
void attn_kernel(const float* __restrict__ TPG, unsigned short* __restrict__ ctx,
                 int Nn, float smult, float gmult, float scmult) {
  __shared__ float sTh[128 * 16];
  __shared__ float sPh[128 * 16];
  __shared__ float sGc[128 * 17];
  __shared__ float sS[256];
  __shared__ float sA[256];
  const int b = blockIdx.x, tid = threadIdx.x;
  const int t = tid >> 4, s = tid & 15;
  double acc = 0.0;
  for (int cc = 0; cc < 8; cc++) {
#pragma unroll
    for (int i = 0; i < 2; i++) {
      int fi = i * 256 + tid, r = fi >> 2, c = (fi & 3) * 4;
      *(floatx4*)&sTh[r * 16 + c] =
          *(const floatx4*)&TPG[(size_t)(cc * 128 + r) * Nn + b * 16 + c];
      *(floatx4*)&sPh[r * 16 + c] =
          *(const floatx4*)&TPG[(size_t)(1024 + cc * 128 + r) * Nn + b * 16 + c];
    }
    __syncthreads();
    for (int o = 0; o < 128; o++)
      acc += (double)sTh[o * 16 + t] * (double)sPh[o * 16 + s];
    __syncthreads();
  }
  float sv = (float)(acc * (double)smult);
  sS[tid] = sv;
  __syncthreads();
  float mx = sS[t * 16];
#pragma unroll
  for (int j = 1; j < 16; j++) mx = fmaxf(mx, sS[t * 16 + j]);
  float e = expf(sv - mx);
  sA[tid] = e;
  __syncthreads();
  float sum = 0.f;
#pragma unroll
  for (int j = 0; j < 16; j++) sum += sA[t * 16 + j];
  float alpha = e / sum;
  __syncthreads();
  sA[tid] = alpha;
  __syncthreads();
  const int t2 = tid >> 7, ol = tid & 127;
  for (int cc = 0; cc < 8; cc++) {
#pragma unroll
    for (int i = 0; i < 2; i++) {
      int fi = i * 256 + tid, r = fi >> 2, c = (fi & 3) * 4;
      floatx4 g = *(const floatx4*)&TPG[(size_t)(2048 + cc * 128 + r) * Nn + b * 16 + c];
      sGc[r * 17 + c + 0] = g[0] * gmult;
      sGc[r * 17 + c + 1] = g[1] * gmult;
      sGc[r * 17 + c + 2] = g[2] * gmult;
      sGc[r * 17 + c + 3] = g[3] * gmult;
    }
    __syncthreads();
#pragma unroll
    for (int tt = 0; tt < 8; tt++) {
      int tc = t2 + tt * 2;
      float cv = 0.f;
#pragma unroll
      for (int s2 = 0; s2 < 16; s2++) cv += sA[tc * 16 + s2] * sGc[ol * 17 + s2];
      float cs = cv * scmult;
      _Float16 chh = (_Float16)cs;
      _Float16 cll = (_Float16)(cs - (float)chh);
      size_t base = ((size_t)b * 16 + tc) * 2048 + cc * 128 + ol;
      ctx[base] = h_bits(chh);
      ctx[base + 1024] = h_bits(cll);
    }
    __syncthreads();
  }
}

// ---------------------------------------------------------------------------
// Elementwise / transpose / prep kernels
// ---------------------------------------------------------------------------
__global__ __launch_bounds__(256)
void e0_kernel(const float* __restrict__ x, float* __restrict__ h,
               unsigned short* __restrict__ u2, const float* __restrict__ tbl,
               int b0, float uscale) {
  __shared__ float sx[16 * 129];
  const int bl = blockIdx.x, d0 = blockIdx.y * 128, tid = threadIdx.x;
  const float* xb = x + (size_t)(b0 + bl) * 32768;
#pragma unroll
  for (int i = 0; i < 2; i++) {
    int fi = i * 256 + tid, r = fi >> 2, c = (fi & 3) * 4;
    floatx4 v = *(const floatx4*)&xb[(d0 + r) * 16 + c];
    sx[(c + 0) * 129 + r] = v[0];
    sx[(c + 1) * 129 + r] = v[1];
    sx[(c + 2) * 129 + r] = v[2];
    sx[(c + 3) * 129 + r] = v[3];
  }
  __syncthreads();
  const int t4 = tid >> 6, dl = (tid & 63) * 2;
#pragma unroll
  for (int i = 0; i < 4; i++) {
    int t = t4 * 4 + i;
    int d = d0 + dl;
    float x0 = sx[t * 129 + dl], x1 = sx[t * 129 + dl + 1];
    size_t n = (size_t)bl * 16 + t;
    floatx2 hv; hv[0] = x0; hv[1] = x1;
    *(floatx2*)&h[n * 2048 + d] = hv;
    float i0 = tbl[d], i1 = tbl[d + 1], q0 = tbl[2048 + d], q1 = tbl[2048 + d + 1];
    float u0 = __fadd_rn(__fmul_rn(x0, i0), q0) * uscale;
    float u1 = __fadd_rn(__fmul_rn(x1, i1), q1) * uscale;
    _Float16 a0 = (_Float16)u0, a1 = (_Float16)u1;
    ushort2v uv; uv[0] = h_bits(a0); uv[1] = h_bits(a1);
    *(ushort2v*)&u2[n * 4096 + d] = uv;
    ushort2v lv;
    lv[0] = h_bits((_Float16)(u0 - (float)a0));
    lv[1] = h_bits((_Float16)(u1 - (float)a1));
    *(ushort2v*)&u2[n * 4096 + 2048 + d] = lv;
  }
}

__global__ __launch_bounds__(256)
void f1_kernel(const float* __restrict__ x, const float* __restrict__ h,
               unsigned short* __restrict__ r, const float* __restrict__ tbl, int b0) {
  __shared__ float sx[16 * 129];
  const int bl = blockIdx.x, d0 = blockIdx.y * 128, tid = threadIdx.x;
  const float* xb = x + (size_t)(b0 + bl) * 32768;
#pragma unroll
  for (int i = 0; i < 2; i++) {
    int fi = i * 256 + tid, rr = fi >> 2, c = (fi & 3) * 4;
    floatx4 v = *(const floatx4*)&xb[(d0 + rr) * 16 + c];
    sx[(c + 0) * 129 + rr] = v[0];
    sx[(c + 1) * 129 + rr] = v[1];
    sx[(c + 2) * 129 + rr] = v[2];
    sx[(c + 3) * 129 + rr] = v[3];
  }
  __syncthreads();
  const int t4 = tid >> 6, dl = (tid & 63) * 2;
#pragma unroll
  for (int i = 0; i < 4; i++) {
    int t = t4 * 4 + i;
    int d = d0 + dl;
    size_t n = (size_t)bl * 16 + t;
    floatx2 hv = *(const floatx2*)&h[n * 2048 + d];
    float i0 = tbl[d], i1 = tbl[d + 1], q0 = tbl[2048 + d], q1 = tbl[2048 + d + 1];
    float v0 = __fadd_rn(__fadd_rn(__fmul_rn(hv[0], i0), q0), sx[t * 129 + dl]);
    float v1 = __fadd_rn(__fadd_rn(__fmul_rn(hv[1], i1), q1), sx[t * 129 + dl + 1]);
    v0 = fmaxf(v0, 0.f);
    v1 = fmaxf(v1, 0.f);
    ushort2v rv;
    rv[0] = h_bits((_Float16)(v0 * 0x1p-14f));
    rv[1] = h_bits((_Float16)(v1 * 0x1p-14f));
    *(ushort2v*)&r[(size_t)(b0 + bl) * 32768 + (size_t)t * 2048 + d] = rv;
  }
}

__global__ __launch_bounds__(256)
void prep_tbl(const float* __restrict__ g, const float* __restrict__ be,
              const float* __restrict__ me, const float* __restrict__ va,
              float* __restrict__ tbl) {
  int d = blockIdx.x * 256 + threadIdx.x;
  if (d < 2048) {
    float inv = g[d] / sqrtf(va[d] + 1e-5f);
    tbl[d] = inv;
    tbl[2048 + d] = __fsub_rn(be[d], __fmul_rn(me[d], inv));
  }
}

__global__ __launch_bounds__(256)
void prep_qkv(const float* __restrict__ th, const float* __restrict__ ph,
              const float* __restrict__ gw, unsigned short* __restrict__ A1w) {
  int i = (blockIdx.x * 256 + threadIdx.x) * 4;
  int row = i >> 11, d = i & 2047;
  const float* src = (row < 1024) ? (th + (size_t)row * 2048 + d)
                   : (row < 2048) ? (ph + (size_t)(row - 1024) * 2048 + d)
                                  : (gw + (size_t)(row - 2048) * 2048 + d);
  floatx4 v = *(const floatx4*)src;
  ushort4v hi, lo;
#pragma unroll
  for (int j = 0; j < 4; j++) {
    float sc = v[j] * 4096.f;
    _Float16 hh = (_Float16)sc;
    hi[j] = h_bits(hh);
    lo[j] = h_bits((_Float16)(sc - (float)hh));
  }
  size_t base = (size_t)row * 4096 + d;
  *(ushort4v*)&A1w[base] = hi;
  *(ushort4v*)&A1w[base + 2048] = lo;
}

__global__ __launch_bounds__(256)
void prep_wc(const float* __restrict__ Ww, unsigned short* __restrict__ Wc2) {
  int i = (blockIdx.x * 256 + threadIdx.x) * 4;
  int row = i >> 10, o = i & 1023;
  floatx4 v = *(const floatx4*)&Ww[(size_t)row * 1024 + o];
  ushort4v hi, lo;
#pragma unroll
  for (int j = 0; j < 4; j++) {
    float sc = v[j] * 4096.f;
    _Float16 hh = (_Float16)sc;
    hi[j] = h_bits(hh);
    lo[j] = h_bits((_Float16)(sc - (float)hh));
  }
  size_t base = (size_t)row * 2048 + o;
  *(ushort4v*)&Wc2[base] = hi;
  *(ushort4v*)&Wc2[base + 1024] = lo;
}

__global__ __launch_bounds__(256)
void prep_w1p(const float* __restrict__ w1, unsigned short* __restrict__ w1p) {
  __shared__ float sx[16 * 129];
  const int oc = blockIdx.x, d0 = blockIdx.y * 128, tid = threadIdx.x;
  const float* wb = w1 + (size_t)oc * 32768;
#pragma unroll
  for (int i = 0; i < 2; i++) {
    int fi = i * 256 + tid, rr = fi >> 2, c = (fi & 3) * 4;
    floatx4 v = *(const floatx4*)&wb[(d0 + rr) * 16 + c];
    sx[(c + 0) * 129 + rr] = v[0];
    sx[(c + 1) * 129 + rr] = v[1];
    sx[(c + 2) * 129 + rr] = v[2];
    sx[(c + 3) * 129 + rr] = v[3];
  }
  __syncthreads();
  const int t4 = tid >> 6, dl = (tid & 63) * 2;
#pragma unroll
  for (int i = 0; i < 4; i++) {
    int t = t4 * 4 + i, d = d0 + dl;
    ushort2v wv;
    wv[0] = h_bits((_Float16)sx[t * 129 + dl]);
    wv[1] = h_bits((_Float16)sx[t * 129 + dl + 1]);
    *(ushort2v*)&w1p[(size_t)oc * 32768 + (size_t)t * 2048 + d] = wv;
  }
}

__global__ __launch_bounds__(256)
void prep_w2t(const float* __restrict__ w2, float* __restrict__ w2t) {
  int o = blockIdx.x, tid = threadIdx.x;
  if (tid < 174) w2t[(size_t)o * 174 + tid] = w2[(size_t)tid * 512 + o];
}

__global__ __launch_bounds__(256)
void fc1red(const float* __restrict__ p, const float* __restrict__ b1,
            float* __restrict__ r1) {
  int i = blockIdx.x * 256 + threadIdx.x;
  int o = i & 511;
  const size_t S = (size_t)2048 * 512;
  float v = p[i] + p[i + S] + p[i + 2 * S] + p[i + 3 * S];
  v = v * 16384.f + b1[o];  // undo r*2^-14 scaling
  r1[i] = fmaxf(v, 0.f);
}

__global__ __launch_bounds__(256)
void fc2_kernel(const float* __restrict__ r1, const float* __restrict__ w2t,
                const float* __restrict__ b2, float* __restrict__ out) {
  __shared__ float sR[512];
  const int b = blockIdx.x, tid = threadIdx.x;
  sR[tid] = r1[(size_t)b * 512 + tid];
  sR[tid + 256] = r1[(size_t)b * 512 + tid + 256];
  __syncthreads();
  if (tid < 174) {
    float a = b2[tid];
    for (int o = 0; o < 512; o++) a += sR[o] * w2t[o * 174 + tid];
    out[(size_t)b * 174 + tid] = a;
  }
}

// ---------------------------------------------------------------------------
extern "C" void kernel_launch(void* const* d_in, const int* in_sizes, int n_in,
                              void* d_out, int out_size, void* d_ws, size_t ws_size,
                              hipStream_t stream) {
  const float* x = (const float*)d_in[0];
  const float* thw = (const float*)d_in[1];
  const float* phw = (const float*)d_in[2];
  const float* gw = (const float*)d_in[3];
  const float* Ww = (const float*)d_in[4];
  const float* gam = (const float*)d_in[5];
  const float* bet = (const float*)d_in[6];
  const float* mea = (const float*)d_in[7];
  const float* var = (const float*)d_in[8];
  const float* w1 = (const float*)d_in[9];
  const float* b1 = (const float*)d_in[10];
  const float* w2 = (const float*)d_in[11];
  const float* b2 = (const float*)d_in[12];

  auto AL = [](size_t v) { return (v + 255) & ~(size_t)255; };
  const size_t fixed = AL((size_t)2048 * 32768 * 2)   // rbuf
                     + AL((size_t)3072 * 4096 * 2)    // A1w
                     + AL((size_t)2048 * 2048 * 2)    // Wc2
                     + AL((size_t)512 * 32768 * 2)    // w1p
                     + AL((size_t)4 * 2048 * 512 * 4) // r1 partials
                     + AL((size_t)2048 * 512 * 4)     // r1
                     + AL((size_t)512 * 174 * 4)      // w2t
                     + AL((size_t)4096 * 4);          // tbl
  int nsplit = 16;
  for (int cand : {1, 2, 4, 8, 16}) {
    size_t Nn_ = (size_t)32768 / cand;
    size_t per = AL(Nn_ * 2048 * 4) + AL(Nn_ * 4096 * 2) +
                 AL((size_t)3072 * Nn_ * 4) + AL(Nn_ * 2048 * 2);
    if (fixed + per <= ws_size) { nsplit = cand; break; }
  }
  const int Nb = 2048 / nsplit;
  const int Nn = Nb * 16;

  char* pp = (char*)d_ws;
  auto take = [&](size_t n) { char* q = pp; pp += (n + 255) & ~(size_t)255; return q; };
  unsigned short* rbuf = (unsigned short*)take((size_t)2048 * 32768 * 2);
  unsigned short* A1w = (unsigned short*)take((size_t)3072 * 4096 * 2);
  unsigned short* Wc2 = (unsigned short*)take((size_t)2048 * 2048 * 2);
  unsigned short* w1p = (unsigned short*)take((size_t)512 * 32768 * 2);
  float* r1p = (float*)take((size_t)4 * 2048 * 512 * 4);
  float* r1 = (float*)take((size_t)2048 * 512 * 4);
  float* w2t = (float*)take((size_t)512 * 174 * 4);
  float* tbl = (float*)take((size_t)4096 * 4);
  float* h = (float*)take((size_t)Nn * 2048 * 4);
  unsigned short* u2 = (unsigned short*)take((size_t)Nn * 4096 * 2);
  float* TPG = (float*)take((size_t)3072 * Nn * 4);
  unsigned short* ctxb = (unsigned short*)take((size_t)Nn * 2048 * 2);

  // per-iteration pow2 scale exponents for u-hat = u * 2^-k  (fp16 range)
  static const int ks[17] = {0, 0, 0, 0, 0, 0, 0, 0, 2, 3, 5, 7, 8, 10, 11, 13, 15};

  prep_tbl<<<8, 256, 0, stream>>>(gam, bet, mea, var, tbl);
  prep_qkv<<<6144, 256, 0, stream>>>(thw, phw, gw, A1w);
  prep_wc<<<2048, 256, 0, stream>>>(Ww, Wc2);
  prep_w1p<<<dim3(512, 16), 256, 0, stream>>>(w1, w1p);
  prep_w2t<<<512, 256, 0, stream>>>(w2, w2t);

  for (int sp = 0; sp < nsplit; sp++) {
    int b0 = sp * Nb;
    e0_kernel<<<dim3(Nb, 16), 256, 0, stream>>>(x, h, u2, tbl, b0, 1.0f);
    for (int it = 0; it < 16; it++) {
      // QKV+G: [3072][hi|lo 2048] x u2 [Nn][hi|lo 2048] -> TPG fp32
      gemm_f16<3, 0><<<dim3(24, Nn / 128), 256, 0, stream>>>(
          A1w, 4096, u2, 4096, 2048, TPG, nullptr, Nn, nullptr,
          0.f, 0.f, 0, 0, 0);
      attn_kernel<<<dim3(Nb), 256, 0, stream>>>(
          TPG, ctxb, Nn,
          ldexpf(1.f, 2 * ks[it] - 34),   // score unscale / 1024
          ldexpf(1.f, ks[it] - 12),       // g unscale
          ldexpf(1.f, -ks[it] - 2));      // context scale
      // W-path: ctx [Nn][hi|lo 1024] x Wc2 [2048][hi|lo 1024] -> h + next u2
      gemm_f16<3, 2><<<dim3(Nn / 128, 16), 256, 0, stream>>>(
          ctxb, 2048, Wc2, 2048, 1024, h, u2, 2048, tbl,
          ldexpf(1.f, ks[it] - 10),       // ctx unscale
          ldexpf(1.f, -ks[it + 1]),       // next-u scale
          (it < 15) ? 1 : 0, 0, 0);
    }
    f1_kernel<<<dim3(Nb, 16), 256, 0, stream>>>(x, h, rbuf, tbl, b0);
  }

  // fc1: [2048][32768] x [512][32768], split-K over blockIdx.z (4 x 8192)
  gemm_f16<1, 0><<<dim3(16, 4, 4), 256, 0, stream>>>(
      rbuf, 32768, w1p, 32768, 8192, r1p, nullptr, 512, nullptr,
      0.f, 0.f, 0, 8192, (long)2048 * 512);
  fc1red<<<4096, 256, 0, stream>>>(r1p, b1, r1);
  fc2_kernel<<<2048, 256, 0, stream>>>(r1, w2t, b2, (float*)d_out);
}